// Round 8
// baseline (179.119 us; speedup 1.0000x reference)
//
#include <hip/hip_runtime.h>

// GraphNeuralNetwork: 4 layers of gather(src)*w -> scatter_add(dst) -> +bias -> relu
// B=256, N=8192, E=262144 (2^18), fp32 in/out.
// Round 7: XCD-localized gather. blockIdx&7 = batch slice (32 cols); with the
// round-robin workgroup->XCD dispatch each XCD re-reads only its 512KB act slice
// (L2-resident, ~32x line reuse) instead of pulling all 4MB cross-XCD per layer
// (32MB -> 4MB/layer act fabric traffic). csr split into srcs[u16]+wts[f32]
// (6B/edge, re-streamed once per slice = 12MB/layer from L3). Theory test:
// if cross-XCD line fills were the gather wall, ~2x on gather; if neutral,
// the wall is per-CU issue/L1 and this round falsifies the fabric theory.

static constexpr int BATCH = 256;
static constexpr int NN    = 8192;
static constexpr int NE    = 262144;   // 2^18
static constexpr int NL    = 4;
static constexpr int NBUK  = 128;      // coarse buckets per layer (64 dst rows each)
static constexpr int BCAP  = 3072;     // staging capacity per bucket
static constexpr int CHUNK = 2048;     // edges per block in pass 1

__device__ inline unsigned bf16rne(float f) {  // f32 -> bf16 bits, round-nearest-even
  unsigned u = __float_as_uint(f);
  return (u + 0x7fffu + ((u >> 16) & 1u)) >> 16;
}
__device__ inline float bf16tof(unsigned us) { return __uint_as_float(us << 16); }
__device__ inline float blo(unsigned u) { return __uint_as_float(u << 16); }
__device__ inline float bhi(unsigned u) { return __uint_as_float(u & 0xffff0000u); }

// ---- f32 [B,N] -> bf16 [N,B] ----
__global__ void transpose_in_k(const float* __restrict__ in, ushort* __restrict__ out) {
  __shared__ float tile[32][33];
  int c0 = blockIdx.x * 32, r0 = blockIdx.y * 32;   // c0 over N, r0 over B
  int tx = threadIdx.x, ty = threadIdx.y;
#pragma unroll
  for (int i = ty; i < 32; i += 8)
    tile[i][tx] = in[(size_t)(r0 + i) * NN + (c0 + tx)];
  __syncthreads();
#pragma unroll
  for (int i = ty; i < 32; i += 8)
    out[(size_t)(c0 + i) * BATCH + (r0 + tx)] = (ushort)bf16rne(tile[tx][i]);
}

// ---- bf16 [N,B] -> f32 [B,N] ----
__global__ void transpose_out_k(const ushort* __restrict__ in, float* __restrict__ out) {
  __shared__ float tile[32][33];
  int c0 = blockIdx.x * 32, r0 = blockIdx.y * 32;   // c0 over B, r0 over N
  int tx = threadIdx.x, ty = threadIdx.y;
#pragma unroll
  for (int i = ty; i < 32; i += 8)
    tile[i][tx] = bf16tof(in[(size_t)(r0 + i) * BATCH + (c0 + tx)]);
  __syncthreads();
#pragma unroll
  for (int i = ty; i < 32; i += 8)
    out[(size_t)(c0 + i) * NN + (r0 + tx)] = tile[tx][i];
}

// ---- tiny zero kernel (replaces rocclr fillBuffer) ----
__global__ void zero_k(int* __restrict__ p) { p[threadIdx.x] = 0; }

// ---- Pass 1: partition edges into coarse buckets, block-ordered coalesced writes ----
__global__ void part_k(const int* __restrict__ src, const int* __restrict__ dst,
                       const float* __restrict__ w, int* __restrict__ bcur,
                       uint2* __restrict__ stag) {
  __shared__ int cnt[NBUK], sc[NBUK], loff[NBUK], gbase[NBUK], lcur[NBUK];
  __shared__ uint2 ebuf[CHUNK];
  __shared__ unsigned char bkt[CHUNK];
  int t = threadIdx.x;
  int l = blockIdx.x >> 7;                 // 128 blocks per layer
  size_t e0 = (size_t)blockIdx.x * CHUNK;
  if (t < NBUK) cnt[t] = 0;
  __syncthreads();
  int es[8], ed[8]; float ew[8];
#pragma unroll
  for (int k = 0; k < 8; ++k) {
    size_t e = e0 + t + k * 256;
    es[k] = src[e]; ed[k] = dst[e]; ew[k] = w[e];
    atomicAdd(&cnt[ed[k] >> 6], 1);
  }
  __syncthreads();
  if (t < NBUK) sc[t] = cnt[t];
  __syncthreads();
  for (int off = 1; off < NBUK; off <<= 1) {   // inclusive scan (all threads barrier)
    int v = 0;
    if (t < NBUK && t >= off) v = sc[t - off];
    __syncthreads();
    if (t < NBUK) sc[t] += v;
    __syncthreads();
  }
  if (t < NBUK) {
    int excl = sc[t] - cnt[t];
    loff[t] = excl;
    lcur[t] = excl;
    gbase[t] = atomicAdd(&bcur[(l << 7) + t], cnt[t]);   // one atomic per (block,bucket)
  }
  __syncthreads();
#pragma unroll
  for (int k = 0; k < 8; ++k) {
    int b = ed[k] >> 6;
    int p = atomicAdd(&lcur[b], 1);          // LDS atomic, block-local ordering
    ebuf[p] = make_uint2((unsigned)es[k] | ((unsigned)(ed[k] & 63) << 16),
                         __float_as_uint(ew[k]));
    bkt[p]  = (unsigned char)b;
  }
  __syncthreads();
#pragma unroll
  for (int k = 0; k < 8; ++k) {              // coalesced run writes (avg 16-edge runs)
    int i = t + k * 256;
    int b = bkt[i];
    int gp = gbase[b] + (i - loff[b]);
    if (gp < BCAP)                           // statistically impossible overflow guard
      stag[(size_t)((l << 7) + b) * BCAP + gp] = ebuf[i];
  }
}

// ---- Pass 2: one block per bucket -> final csr segments (srcs u16 + wts f32) ----
__global__ void place_k(const uint2* __restrict__ stag, const int* __restrict__ bcur,
                        ushort* __restrict__ srcs, float* __restrict__ wts,
                        int* __restrict__ rp) {
  __shared__ int bc[NBUK], bsc[NBUK];
  __shared__ int cnt[64], sc64[64], lcur[64];
  __shared__ uint2 ebuf[BCAP];
  int t = threadIdx.x;
  int gb = blockIdx.x, l = gb >> 7, b = gb & 127;
  if (t < NBUK) { bc[t] = min(bcur[(l << 7) + t], BCAP); bsc[t] = bc[t]; }
  if (t < 64) cnt[t] = 0;
  __syncthreads();
  for (int off = 1; off < NBUK; off <<= 1) {   // inclusive scan of bucket counts
    int v = 0;
    if (t < NBUK && t >= off) v = bsc[t - off];
    __syncthreads();
    if (t < NBUK) bsc[t] += v;
    __syncthreads();
  }
  int n   = bc[b];
  int seg = bsc[b] - bc[b];                    // exclusive base within layer csr
  for (int i = t; i < n; i += 256)             // coalesced staging read
    ebuf[i] = stag[(size_t)gb * BCAP + i];
  __syncthreads();
  for (int i = t; i < n; i += 256)
    atomicAdd(&cnt[(ebuf[i].x >> 16) & 63], 1);
  __syncthreads();
  if (t < 64) sc64[t] = cnt[t];
  __syncthreads();
  for (int off = 1; off < 64; off <<= 1) {     // inclusive scan of 64 row counts
    int v = 0;
    if (t < 64 && t >= off) v = sc64[t - off];
    __syncthreads();
    if (t < 64) sc64[t] += v;
    __syncthreads();
  }
  if (t < 64) {
    int excl = sc64[t] - cnt[t];
    lcur[t] = excl;
    rp[l * (NN + 1) + (b << 6) + t] = seg + excl;
  }
  if (b == 127 && t == 65) rp[l * (NN + 1) + NN] = bsc[127];  // layer total (== NE)
  __syncthreads();
  for (int i = t; i < n; i += 256) {           // scatter within contiguous segment
    uint2 r = ebuf[i];
    int p = atomicAdd(&lcur[(r.x >> 16) & 63], 1);
    srcs[(size_t)l * NE + seg + p] = (ushort)(r.x & 0xffffu);
    wts [(size_t)l * NE + seg + p] = __uint_as_float(r.y);
  }
}

// ---- per-layer gather, XCD-sliced ----
// blockIdx&7 = batch slice (32 cols): all blocks of a slice land on one XCD
// (round-robin dispatch), so act reads hit that XCD's L2 (512KB slice, ~32x
// line reuse). Wave = 1 dst row: 16 lanes x 2 cols per edge, 4 edge slots.
__global__ void gather_k(const ushort* __restrict__ act, ushort* __restrict__ out,
                         const ushort* __restrict__ srcs, const float* __restrict__ wts,
                         const int* __restrict__ rp, const float* __restrict__ bias) {
  int slice = blockIdx.x & 7;
  int row   = (blockIdx.x >> 3) * 4 + (threadIdx.x >> 6);
  int lane  = threadIdx.x & 63;
  int cp    = lane & 15;                   // col-pair id (2 bf16 cols)
  int slot  = lane >> 4;                   // edge slot 0..3
  int k0 = rp[row], k1 = rp[row + 1];
  float2 acc = make_float2(0.f, 0.f);
  const ushort* actc = act + slice * 32 + cp * 2;
  for (int kc = k0; kc < k1; kc += 64) {
    int nk = k1 - kc;
    if (nk > 64) nk = 64;
    int ksel = lane < nk ? lane : nk - 1;  // guarded coalesced metadata load
    int   sv = srcs[kc + ksel];
    float wv = wts[kc + ksel];
    int niter = (nk + 3) >> 2;
#pragma unroll 4
    for (int j = 0; j < niter; ++j) {
      int  idx   = 4 * j + slot;
      bool valid = idx < nk;
      int  qi    = valid ? idx : 0;
      int   se = __shfl(sv, qi);
      float wt = __shfl(wv, qi);
      wt = valid ? wt : 0.f;
      unsigned v = *(const unsigned*)(actc + (size_t)se * BATCH);
      acc.x += wt * blo(v);
      acc.y += wt * bhi(v);
    }
  }
  // reduce the 4 edge-slot partials (lanes l, l^16, l^32, l^48)
  acc.x += __shfl_xor(acc.x, 16); acc.x += __shfl_xor(acc.x, 32);
  acc.y += __shfl_xor(acc.y, 16); acc.y += __shfl_xor(acc.y, 32);
  if (slot == 0) {
    float b = bias[row];
    unsigned o = bf16rne(fmaxf(acc.x + b, 0.f)) |
                 (bf16rne(fmaxf(acc.y + b, 0.f)) << 16);
    *(unsigned*)(out + (size_t)row * BATCH + slice * 32 + cp * 2) = o;
  }
}

extern "C" void kernel_launch(void* const* d_in, const int* in_sizes, int n_in,
                              void* d_out, int out_size, void* d_ws, size_t ws_size,
                              hipStream_t stream) {
  const float* x       = (const float*)d_in[0];  // [B, N]
  const float* weights = (const float*)d_in[1];  // [L, E]
  const float* bias    = (const float*)d_in[2];  // [L, N]
  const int*   esrc    = (const int*)d_in[3];    // [L, E]
  const int*   edst    = (const int*)d_in[4];    // [L, E]
  float*       out     = (float*)d_out;          // [B, N]

  // workspace: srcs | wts | row_ptr | bcur | region{stag (12MB) aliases actA+actB}
  char* p = (char*)d_ws;
  ushort* srcs    = (ushort*)p; p += (size_t)NL * NE * 2;            // 2 MB
  float*  wts     = (float*)p;  p += (size_t)NL * NE * 4;            // 4 MB
  int*    row_ptr = (int*)p;    p += (size_t)NL * (NN + 1) * 4;
  int*    bcur    = (int*)p;    p += (size_t)NL * NBUK * 4 + 64;
  uint2*  stag    = (uint2*)p;                                       // 12 MB (build)
  ushort* actA    = (ushort*)p;                                      // 4 MB (gather)
  ushort* actB    = actA + (size_t)NN * BATCH;                       // 4 MB

  // ---- build CSR (before transpose_in: staging aliases act buffers) ----
  zero_k<<<1, NL * NBUK, 0, stream>>>(bcur);
  part_k<<<(NL * NE) / CHUNK, 256, 0, stream>>>(esrc, edst, weights, bcur, stag);
  place_k<<<NL * NBUK, 256, 0, stream>>>(stag, bcur, srcs, wts, row_ptr);

  // ---- x [B,N] f32 -> actA [N,B] bf16 (overwrites staging; build is done) ----
  transpose_in_k<<<dim3(NN / 32, BATCH / 32), dim3(32, 8), 0, stream>>>(x, actA);

  for (int l = 0; l < NL; ++l) {
    gather_k<<<(NN / 4) * 8, 256, 0, stream>>>(actA, actB,
                                               srcs + (size_t)l * NE,
                                               wts + (size_t)l * NE,
                                               row_ptr + (size_t)l * (NN + 1),
                                               bias + (size_t)l * NN);
    ushort* t = actA; actA = actB; actB = t;
  }

  // actA [N,B] bf16 -> out [B,N] f32
  transpose_out_k<<<dim3(BATCH / 32, NN / 32), dim3(32, 8), 0, stream>>>(actA, out);
}

// Round 10
// 133.657 us; speedup vs baseline: 1.3401x; 1.3401x over previous
//
#include <hip/hip_runtime.h>

// GraphNeuralNetwork: 4 layers of gather(src)*w -> scatter_add(dst) -> +bias -> relu
// B=256, N=8192, E=262144 (2^18), fp32 in/out.
// Round 9: round 8 with the shfl type bug fixed (float wt = __int_as_float(
// __shfl(wv,...)) — r8 accidentally did int->float CONVERSION of weight bits,
// overflowing to inf). Experiment unchanged: 4 batch slices of 64 cols (1MB
// hot set << 4MB L2) at constant load-instruction count; 8 lanes x 16B per
// edge, 8 edge slots per wave-iter. Build/transposes identical to round 6.

static constexpr int BATCH = 256;
static constexpr int NN    = 8192;
static constexpr int NE    = 262144;   // 2^18
static constexpr int NL    = 4;
static constexpr int NBUK  = 128;      // coarse buckets per layer (64 dst rows each)
static constexpr int BCAP  = 3072;     // staging capacity per bucket
static constexpr int CHUNK = 2048;     // edges per block in pass 1

__device__ inline unsigned bf16rne(float f) {  // f32 -> bf16 bits, round-nearest-even
  unsigned u = __float_as_uint(f);
  return (u + 0x7fffu + ((u >> 16) & 1u)) >> 16;
}
__device__ inline float bf16tof(unsigned us) { return __uint_as_float(us << 16); }
__device__ inline float blo(unsigned u) { return __uint_as_float(u << 16); }
__device__ inline float bhi(unsigned u) { return __uint_as_float(u & 0xffff0000u); }

// ---- f32 [B,N] -> bf16 [N,B] ----
__global__ void transpose_in_k(const float* __restrict__ in, ushort* __restrict__ out) {
  __shared__ float tile[32][33];
  int c0 = blockIdx.x * 32, r0 = blockIdx.y * 32;   // c0 over N, r0 over B
  int tx = threadIdx.x, ty = threadIdx.y;
#pragma unroll
  for (int i = ty; i < 32; i += 8)
    tile[i][tx] = in[(size_t)(r0 + i) * NN + (c0 + tx)];
  __syncthreads();
#pragma unroll
  for (int i = ty; i < 32; i += 8)
    out[(size_t)(c0 + i) * BATCH + (r0 + tx)] = (ushort)bf16rne(tile[tx][i]);
}

// ---- bf16 [N,B] -> f32 [B,N] ----
__global__ void transpose_out_k(const ushort* __restrict__ in, float* __restrict__ out) {
  __shared__ float tile[32][33];
  int c0 = blockIdx.x * 32, r0 = blockIdx.y * 32;   // c0 over B, r0 over N
  int tx = threadIdx.x, ty = threadIdx.y;
#pragma unroll
  for (int i = ty; i < 32; i += 8)
    tile[i][tx] = bf16tof(in[(size_t)(r0 + i) * BATCH + (c0 + tx)]);
  __syncthreads();
#pragma unroll
  for (int i = ty; i < 32; i += 8)
    out[(size_t)(c0 + i) * NN + (r0 + tx)] = tile[tx][i];
}

// ---- tiny zero kernel (replaces rocclr fillBuffer) ----
__global__ void zero_k(int* __restrict__ p) { p[threadIdx.x] = 0; }

// ---- Pass 1: partition edges into coarse buckets, block-ordered coalesced writes ----
__global__ void part_k(const int* __restrict__ src, const int* __restrict__ dst,
                       const float* __restrict__ w, int* __restrict__ bcur,
                       uint2* __restrict__ stag) {
  __shared__ int cnt[NBUK], sc[NBUK], loff[NBUK], gbase[NBUK], lcur[NBUK];
  __shared__ uint2 ebuf[CHUNK];
  __shared__ unsigned char bkt[CHUNK];
  int t = threadIdx.x;
  int l = blockIdx.x >> 7;                 // 128 blocks per layer
  size_t e0 = (size_t)blockIdx.x * CHUNK;
  if (t < NBUK) cnt[t] = 0;
  __syncthreads();
  int es[8], ed[8]; float ew[8];
#pragma unroll
  for (int k = 0; k < 8; ++k) {
    size_t e = e0 + t + k * 256;
    es[k] = src[e]; ed[k] = dst[e]; ew[k] = w[e];
    atomicAdd(&cnt[ed[k] >> 6], 1);
  }
  __syncthreads();
  if (t < NBUK) sc[t] = cnt[t];
  __syncthreads();
  for (int off = 1; off < NBUK; off <<= 1) {   // inclusive scan (all threads barrier)
    int v = 0;
    if (t < NBUK && t >= off) v = sc[t - off];
    __syncthreads();
    if (t < NBUK) sc[t] += v;
    __syncthreads();
  }
  if (t < NBUK) {
    int excl = sc[t] - cnt[t];
    loff[t] = excl;
    lcur[t] = excl;
    gbase[t] = atomicAdd(&bcur[(l << 7) + t], cnt[t]);   // one atomic per (block,bucket)
  }
  __syncthreads();
#pragma unroll
  for (int k = 0; k < 8; ++k) {
    int b = ed[k] >> 6;
    int p = atomicAdd(&lcur[b], 1);          // LDS atomic, block-local ordering
    ebuf[p] = make_uint2((unsigned)es[k] | ((unsigned)(ed[k] & 63) << 16),
                         __float_as_uint(ew[k]));
    bkt[p]  = (unsigned char)b;
  }
  __syncthreads();
#pragma unroll
  for (int k = 0; k < 8; ++k) {              // coalesced run writes (avg 16-edge runs)
    int i = t + k * 256;
    int b = bkt[i];
    int gp = gbase[b] + (i - loff[b]);
    if (gp < BCAP)                           // statistically impossible overflow guard
      stag[(size_t)((l << 7) + b) * BCAP + gp] = ebuf[i];
  }
}

// ---- Pass 2: one block per bucket -> final csr segment + row_ptr ----
__global__ void place_k(const uint2* __restrict__ stag, const int* __restrict__ bcur,
                        float2* __restrict__ csr, int* __restrict__ rp) {
  __shared__ int bc[NBUK], bsc[NBUK];
  __shared__ int cnt[64], sc64[64], lcur[64];
  __shared__ uint2 ebuf[BCAP];
  int t = threadIdx.x;
  int gb = blockIdx.x, l = gb >> 7, b = gb & 127;
  if (t < NBUK) { bc[t] = min(bcur[(l << 7) + t], BCAP); bsc[t] = bc[t]; }
  if (t < 64) cnt[t] = 0;
  __syncthreads();
  for (int off = 1; off < NBUK; off <<= 1) {   // inclusive scan of bucket counts
    int v = 0;
    if (t < NBUK && t >= off) v = bsc[t - off];
    __syncthreads();
    if (t < NBUK) bsc[t] += v;
    __syncthreads();
  }
  int n   = bc[b];
  int seg = bsc[b] - bc[b];                    // exclusive base within layer csr
  for (int i = t; i < n; i += 256)             // coalesced staging read
    ebuf[i] = stag[(size_t)gb * BCAP + i];
  __syncthreads();
  for (int i = t; i < n; i += 256)
    atomicAdd(&cnt[(ebuf[i].x >> 16) & 63], 1);
  __syncthreads();
  if (t < 64) sc64[t] = cnt[t];
  __syncthreads();
  for (int off = 1; off < 64; off <<= 1) {     // inclusive scan of 64 row counts
    int v = 0;
    if (t < 64 && t >= off) v = sc64[t - off];
    __syncthreads();
    if (t < 64) sc64[t] += v;
    __syncthreads();
  }
  if (t < 64) {
    int excl = sc64[t] - cnt[t];
    lcur[t] = excl;
    rp[l * (NN + 1) + (b << 6) + t] = seg + excl;
  }
  if (b == 127 && t == 65) rp[l * (NN + 1) + NN] = bsc[127];  // layer total (== NE)
  __syncthreads();
  for (int i = t; i < n; i += 256) {           // scatter within 16KB segment (L2 combines)
    uint2 r = ebuf[i];
    int p = atomicAdd(&lcur[(r.x >> 16) & 63], 1);
    csr[(size_t)l * NE + seg + p] =
        make_float2(__int_as_float((int)(r.x & 0xffffu)), __uint_as_float(r.y));
  }
}

// ---- per-layer gather, 4 slice phases of 64 cols (1MB hot set) ----
// slice = blockIdx>>11 (slice-major ordering -> grid phases through one hot set
// at a time). Wave = 1 dst row-slice: 8 lanes x 16B (8 bf16 cols) per edge,
// 8 edge slots per wave-iter; metadata via per-lane-index __shfl (ds_bpermute).
// Load-instr count per layer = E/2 (same as r6); VALU per edge ~halved.
__global__ __launch_bounds__(256) void
gather_k(const ushort* __restrict__ act, ushort* __restrict__ out,
         const float2* __restrict__ csr, const int* __restrict__ rp,
         const float* __restrict__ bias) {
  int slice = blockIdx.x >> 11;                    // 4 slices x 2048 blocks
  int rowblk = blockIdx.x & 2047;
  int row  = rowblk * 4 + (threadIdx.x >> 6);      // 4 waves/block
  int lane = threadIdx.x & 63;
  int slot = lane >> 3;                            // edge slot 0..7
  int cp   = lane & 7;                             // col octet within slice
  int k0 = rp[row], k1 = rp[row + 1];
  float4 a0 = make_float4(0.f, 0.f, 0.f, 0.f);     // cols cp*8+0..3
  float4 a1 = make_float4(0.f, 0.f, 0.f, 0.f);     // cols cp*8+4..7
  const ushort* actc = act + slice * 64 + cp * 8;
  for (int kc = k0; kc < k1; kc += 64) {
    int nk = k1 - kc;
    if (nk > 64) nk = 64;
    int ksel = lane < nk ? lane : nk - 1;          // guarded coalesced metadata load
    unsigned long long mu =
        __builtin_nontemporal_load((const unsigned long long*)(csr + kc + ksel));
    int sv = (int)(mu & 0xffffffffu);
    int wv = (int)(mu >> 32);
    int niter = (nk + 7) >> 3;
#pragma unroll 4
    for (int j = 0; j < niter; ++j) {
      int  idx   = 8 * j + slot;
      bool valid = idx < nk;
      int  qi    = valid ? idx : 0;
      int   s  = __shfl(sv, qi);                   // ds_bpermute, per-lane index
      float wt = __int_as_float(__shfl(wv, qi));   // FIX: bit-reinterpret, not convert
      wt = valid ? wt : 0.f;
      uint4 v = *(const uint4*)(actc + (size_t)s * BATCH);
      a0.x += wt * blo(v.x); a0.y += wt * bhi(v.x);
      a0.z += wt * blo(v.y); a0.w += wt * bhi(v.y);
      a1.x += wt * blo(v.z); a1.y += wt * bhi(v.z);
      a1.z += wt * blo(v.w); a1.w += wt * bhi(v.w);
    }
  }
  // reduce the 8 edge-slot partials (lanes cp, cp^8, cp^16, ..., cp^56)
  a0.x += __shfl_xor(a0.x, 8); a0.x += __shfl_xor(a0.x, 16); a0.x += __shfl_xor(a0.x, 32);
  a0.y += __shfl_xor(a0.y, 8); a0.y += __shfl_xor(a0.y, 16); a0.y += __shfl_xor(a0.y, 32);
  a0.z += __shfl_xor(a0.z, 8); a0.z += __shfl_xor(a0.z, 16); a0.z += __shfl_xor(a0.z, 32);
  a0.w += __shfl_xor(a0.w, 8); a0.w += __shfl_xor(a0.w, 16); a0.w += __shfl_xor(a0.w, 32);
  a1.x += __shfl_xor(a1.x, 8); a1.x += __shfl_xor(a1.x, 16); a1.x += __shfl_xor(a1.x, 32);
  a1.y += __shfl_xor(a1.y, 8); a1.y += __shfl_xor(a1.y, 16); a1.y += __shfl_xor(a1.y, 32);
  a1.z += __shfl_xor(a1.z, 8); a1.z += __shfl_xor(a1.z, 16); a1.z += __shfl_xor(a1.z, 32);
  a1.w += __shfl_xor(a1.w, 8); a1.w += __shfl_xor(a1.w, 16); a1.w += __shfl_xor(a1.w, 32);
  if (slot == 0) {
    float b = bias[row];
    uint4 o;
    o.x = bf16rne(fmaxf(a0.x + b, 0.f)) | (bf16rne(fmaxf(a0.y + b, 0.f)) << 16);
    o.y = bf16rne(fmaxf(a0.z + b, 0.f)) | (bf16rne(fmaxf(a0.w + b, 0.f)) << 16);
    o.z = bf16rne(fmaxf(a1.x + b, 0.f)) | (bf16rne(fmaxf(a1.y + b, 0.f)) << 16);
    o.w = bf16rne(fmaxf(a1.z + b, 0.f)) | (bf16rne(fmaxf(a1.w + b, 0.f)) << 16);
    *(uint4*)(out + (size_t)row * BATCH + slice * 64 + cp * 8) = o;
  }
}

extern "C" void kernel_launch(void* const* d_in, const int* in_sizes, int n_in,
                              void* d_out, int out_size, void* d_ws, size_t ws_size,
                              hipStream_t stream) {
  const float* x       = (const float*)d_in[0];  // [B, N]
  const float* weights = (const float*)d_in[1];  // [L, E]
  const float* bias    = (const float*)d_in[2];  // [L, N]
  const int*   esrc    = (const int*)d_in[3];    // [L, E]
  const int*   edst    = (const int*)d_in[4];    // [L, E]
  float*       out     = (float*)d_out;          // [B, N]

  // workspace: csr | row_ptr | bcur | region{staging (12MB) aliases actA+actB (8MB)}
  char* p = (char*)d_ws;
  float2* csr     = (float2*)p; p += (size_t)NL * NE * 8;            // 8 MB
  int*    row_ptr = (int*)p;    p += (size_t)NL * (NN + 1) * 4;
  int*    bcur    = (int*)p;    p += (size_t)NL * NBUK * 4;
  uint2*  stag    = (uint2*)p;                                       // 12 MB (build phase)
  ushort* actA    = (ushort*)p;                                      // 4 MB (gather phase)
  ushort* actB    = actA + (size_t)NN * BATCH;                       // 4 MB

  // ---- build CSR (before transpose_in: staging aliases act buffers) ----
  zero_k<<<1, NL * NBUK, 0, stream>>>(bcur);
  part_k<<<(NL * NE) / CHUNK, 256, 0, stream>>>(esrc, edst, weights, bcur, stag);
  place_k<<<NL * NBUK, 256, 0, stream>>>(stag, bcur, csr, row_ptr);

  // ---- x [B,N] f32 -> actA [N,B] bf16 (overwrites staging; build is done) ----
  transpose_in_k<<<dim3(NN / 32, BATCH / 32), dim3(32, 8), 0, stream>>>(x, actA);

  for (int l = 0; l < NL; ++l) {
    gather_k<<<(NN / 4) * 4, 256, 0, stream>>>(actA, actB,
                                               csr + (size_t)l * NE,
                                               row_ptr + (size_t)l * (NN + 1),
                                               bias + (size_t)l * NN);
    ushort* t = actA; actA = actB; actB = t;
  }

  // actA [N,B] bf16 -> out [B,N] f32
  transpose_out_k<<<dim3(BATCH / 32, NN / 32), dim3(32, 8), 0, stream>>>(actA, out);
}

// Round 13
// 90.121 us; speedup vs baseline: 1.9875x; 1.4831x over previous
//
#include <hip/hip_runtime.h>

// GraphNeuralNetwork: 4 layers of gather(src)*w -> scatter_add(dst) -> +bias -> relu
// B=256, N=8192, E=262144 (2^18), fp32 in/out.
// Round 12: r11 with the crash fixed. ROOT CAUSE of r10+r11 core dumps: bcur
// zeroing ran in a 256-thread block but NL*NBUK=512 -> bcur[256..511] kept the
// 0xAA ws-poison -> part_k layers 2-3 got gbase≈0xAAAAAAAA (negative) -> the
// `gp < BCAP` int guard passed negative gp -> wild staging writes -> abort.
// Fix: block-0 zero loop covers all 512; guard is now (unsigned)gp < BCAP.
// Experiment unchanged from r11: gather stages each 64-edge metadata chunk
// into a per-wave LDS slot (sanitized), inner loop = ds_read_b64 imm-offset,
// no validity logic. Tests whether gather is issue-bound (~24% instr cut).

static constexpr int BATCH = 256;
static constexpr int NN    = 8192;
static constexpr int NE    = 262144;   // 2^18
static constexpr int NL    = 4;
static constexpr int NBUK  = 128;      // coarse buckets per layer (64 dst rows each)
static constexpr int BCAP  = 3072;     // staging capacity per bucket
static constexpr int CHUNK = 2048;     // edges per block in pass 1

__device__ inline unsigned bf16rne(float f) {  // f32 -> bf16 bits, round-nearest-even
  unsigned u = __float_as_uint(f);
  return (u + 0x7fffu + ((u >> 16) & 1u)) >> 16;
}
__device__ inline float bf16tof(unsigned us) { return __uint_as_float(us << 16); }
__device__ inline float blo(unsigned u) { return __uint_as_float(u << 16); }
__device__ inline float bhi(unsigned u) { return __uint_as_float(u & 0xffff0000u); }

// ---- f32 [B,N] -> bf16 [N,B]; block (0,0) also zeroes ALL 512 bcur entries ----
__global__ void transpose_in_k(const float* __restrict__ in, ushort* __restrict__ out,
                               int* __restrict__ bcur) {
  if (blockIdx.x == 0 && blockIdx.y == 0) {
    int t = threadIdx.y * 32 + threadIdx.x;          // 256 threads
    for (int i = t; i < NL * NBUK; i += 256) bcur[i] = 0;   // 512 entries
  }
  __shared__ float tile[32][33];
  int c0 = blockIdx.x * 32, r0 = blockIdx.y * 32;   // c0 over N, r0 over B
  int tx = threadIdx.x, ty = threadIdx.y;
#pragma unroll
  for (int i = ty; i < 32; i += 8)
    tile[i][tx] = in[(size_t)(r0 + i) * NN + (c0 + tx)];
  __syncthreads();
#pragma unroll
  for (int i = ty; i < 32; i += 8)
    out[(size_t)(c0 + i) * BATCH + (r0 + tx)] = (ushort)bf16rne(tile[tx][i]);
}

// ---- bf16 [N,B] -> f32 [B,N] ----
__global__ void transpose_out_k(const ushort* __restrict__ in, float* __restrict__ out) {
  __shared__ float tile[32][33];
  int c0 = blockIdx.x * 32, r0 = blockIdx.y * 32;   // c0 over B, r0 over N
  int tx = threadIdx.x, ty = threadIdx.y;
#pragma unroll
  for (int i = ty; i < 32; i += 8)
    tile[i][tx] = bf16tof(in[(size_t)(r0 + i) * BATCH + (c0 + tx)]);
  __syncthreads();
#pragma unroll
  for (int i = ty; i < 32; i += 8)
    out[(size_t)(c0 + i) * NN + (r0 + tx)] = tile[tx][i];
}

// ---- Pass 1: partition edges into coarse buckets, block-ordered coalesced writes ----
__global__ void part_k(const int* __restrict__ src, const int* __restrict__ dst,
                       const float* __restrict__ w, int* __restrict__ bcur,
                       uint2* __restrict__ stag) {
  __shared__ int cnt[NBUK], sc[NBUK], loff[NBUK], gbase[NBUK], lcur[NBUK];
  __shared__ uint2 ebuf[CHUNK];
  __shared__ unsigned char bkt[CHUNK];
  int t = threadIdx.x;
  int l = blockIdx.x >> 7;                 // 128 blocks per layer
  size_t e0 = (size_t)blockIdx.x * CHUNK;
  if (t < NBUK) cnt[t] = 0;
  __syncthreads();
  int es[8], ed[8]; float ew[8];
#pragma unroll
  for (int k = 0; k < 8; ++k) {
    size_t e = e0 + t + k * 256;
    es[k] = src[e]; ed[k] = dst[e]; ew[k] = w[e];
    atomicAdd(&cnt[ed[k] >> 6], 1);
  }
  __syncthreads();
  if (t < NBUK) sc[t] = cnt[t];
  __syncthreads();
  for (int off = 1; off < NBUK; off <<= 1) {   // inclusive scan (all threads barrier)
    int v = 0;
    if (t < NBUK && t >= off) v = sc[t - off];
    __syncthreads();
    if (t < NBUK) sc[t] += v;
    __syncthreads();
  }
  if (t < NBUK) {
    int excl = sc[t] - cnt[t];
    loff[t] = excl;
    lcur[t] = excl;
    gbase[t] = atomicAdd(&bcur[(l << 7) + t], cnt[t]);   // one atomic per (block,bucket)
  }
  __syncthreads();
#pragma unroll
  for (int k = 0; k < 8; ++k) {
    int b = ed[k] >> 6;
    int p = atomicAdd(&lcur[b], 1);          // LDS atomic, block-local ordering
    ebuf[p] = make_uint2((unsigned)es[k] | ((unsigned)(ed[k] & 63) << 16),
                         __float_as_uint(ew[k]));
    bkt[p]  = (unsigned char)b;
  }
  __syncthreads();
#pragma unroll
  for (int k = 0; k < 8; ++k) {              // coalesced run writes (avg 16-edge runs)
    int i = t + k * 256;
    int b = bkt[i];
    int gp = gbase[b] + (i - loff[b]);
    if ((unsigned)gp < BCAP)                 // rejects negative AND overflow
      stag[(size_t)((l << 7) + b) * BCAP + gp] = ebuf[i];
  }
}

// ---- Pass 2: one block per bucket -> final csr segment + row_ptr ----
__global__ void place_k(const uint2* __restrict__ stag, const int* __restrict__ bcur,
                        float2* __restrict__ csr, int* __restrict__ rp) {
  __shared__ int bc[NBUK], bsc[NBUK];
  __shared__ int cnt[64], sc64[64], lcur[64];
  __shared__ uint2 ebuf[BCAP];
  int t = threadIdx.x;
  int gb = blockIdx.x, l = gb >> 7, b = gb & 127;
  if (t < NBUK) { bc[t] = min(bcur[(l << 7) + t], BCAP); bsc[t] = bc[t]; }
  if (t < 64) cnt[t] = 0;
  __syncthreads();
  for (int off = 1; off < NBUK; off <<= 1) {   // inclusive scan of bucket counts
    int v = 0;
    if (t < NBUK && t >= off) v = bsc[t - off];
    __syncthreads();
    if (t < NBUK) bsc[t] += v;
    __syncthreads();
  }
  int n   = bc[b];
  int seg = bsc[b] - bc[b];                    // exclusive base within layer csr
  for (int i = t; i < n; i += 256)             // coalesced staging read
    ebuf[i] = stag[(size_t)gb * BCAP + i];
  __syncthreads();
  for (int i = t; i < n; i += 256)
    atomicAdd(&cnt[(ebuf[i].x >> 16) & 63], 1);
  __syncthreads();
  if (t < 64) sc64[t] = cnt[t];
  __syncthreads();
  for (int off = 1; off < 64; off <<= 1) {     // inclusive scan of 64 row counts
    int v = 0;
    if (t < 64 && t >= off) v = sc64[t - off];
    __syncthreads();
    if (t < 64) sc64[t] += v;
    __syncthreads();
  }
  if (t < 64) {
    int excl = sc64[t] - cnt[t];
    lcur[t] = excl;
    rp[l * (NN + 1) + (b << 6) + t] = seg + excl;
  }
  if (b == 127 && t == 65) rp[l * (NN + 1) + NN] = bsc[127];  // layer total (== NE)
  __syncthreads();
  for (int i = t; i < n; i += 256) {           // scatter within 16KB segment (L2 combines)
    uint2 r = ebuf[i];
    int p = atomicAdd(&lcur[(r.x >> 16) & 63], 1);
    csr[(size_t)l * NE + seg + p] =
        make_float2(__int_as_float((int)(r.x & 0xffffu)), __uint_as_float(r.y));
  }
}

// ---- per-layer gather: one wave per dst row; paired edges, LDS metadata ----
// Per 64-edge chunk: one coalesced metadata load, sanitize invalid lanes to
// {s=0,wt=0}, stage to this wave's LDS slot (LDS ops are in-order per wave, no
// barrier). Inner loop: ds_read_b64 at immediate offsets — zero validity logic.
__global__ __launch_bounds__(256) void
gather_k(const ushort* __restrict__ act, ushort* __restrict__ out,
         const float2* __restrict__ csr, const int* __restrict__ rp,
         const float* __restrict__ bias) {
  __shared__ unsigned long long smeta[4][64];      // 512B per wave
  int wid  = threadIdx.x >> 6;
  int row  = blockIdx.x * 4 + wid;                 // 4 waves/block
  int lane = threadIdx.x & 63;
  int half = lane >> 5;
  int l32  = lane & 31;
  int k0 = rp[row], k1 = rp[row + 1];
  float4 accA = make_float4(0.f, 0.f, 0.f, 0.f);   // cols l32*8+0..3
  float4 accB = make_float4(0.f, 0.f, 0.f, 0.f);   // cols l32*8+4..7
  const ushort* actc = act + l32 * 8;
  const unsigned long long* mp = &smeta[wid][half];
  for (int kc = k0; kc < k1; kc += 64) {
    int nk = k1 - kc;
    if (nk > 64) nk = 64;
    int ksel = lane < nk ? lane : 0;               // guarded coalesced load
    unsigned long long mu =
        __builtin_nontemporal_load((const unsigned long long*)(csr + kc + ksel));
    if (lane >= nk) mu = 0ull;                     // sanitize: s=0, wt=0
    smeta[wid][lane] = mu;                         // per-wave slot; in-order DS
    int npair = (nk + 1) >> 1;
#pragma unroll 8
    for (int j = 0; j < npair; ++j) {
      unsigned long long m = mp[2 * j];            // ds_read_b64, imm offset 16j
      int   s  = (int)(m & 0xffffffffu);
      float wt = __uint_as_float((unsigned)(m >> 32));
      uint4 v = *(const uint4*)(actc + (size_t)s * BATCH);
      accA.x += wt * blo(v.x); accA.y += wt * bhi(v.x);
      accA.z += wt * blo(v.y); accA.w += wt * bhi(v.y);
      accB.x += wt * blo(v.z); accB.y += wt * bhi(v.z);
      accB.z += wt * blo(v.w); accB.w += wt * bhi(v.w);
    }
  }
  // merge the two half-wave partial sums (lane <-> lane^32)
  accA.x += __shfl(accA.x, lane ^ 32); accA.y += __shfl(accA.y, lane ^ 32);
  accA.z += __shfl(accA.z, lane ^ 32); accA.w += __shfl(accA.w, lane ^ 32);
  accB.x += __shfl(accB.x, lane ^ 32); accB.y += __shfl(accB.y, lane ^ 32);
  accB.z += __shfl(accB.z, lane ^ 32); accB.w += __shfl(accB.w, lane ^ 32);
  if (half == 0) {
    float b = bias[row];
    uint4 o;
    o.x = bf16rne(fmaxf(accA.x + b, 0.f)) | (bf16rne(fmaxf(accA.y + b, 0.f)) << 16);
    o.y = bf16rne(fmaxf(accA.z + b, 0.f)) | (bf16rne(fmaxf(accA.w + b, 0.f)) << 16);
    o.z = bf16rne(fmaxf(accB.x + b, 0.f)) | (bf16rne(fmaxf(accB.y + b, 0.f)) << 16);
    o.w = bf16rne(fmaxf(accB.z + b, 0.f)) | (bf16rne(fmaxf(accB.w + b, 0.f)) << 16);
    *(uint4*)(out + (size_t)row * BATCH + l32 * 8) = o;
  }
}

extern "C" void kernel_launch(void* const* d_in, const int* in_sizes, int n_in,
                              void* d_out, int out_size, void* d_ws, size_t ws_size,
                              hipStream_t stream) {
  const float* x       = (const float*)d_in[0];  // [B, N]
  const float* weights = (const float*)d_in[1];  // [L, E]
  const float* bias    = (const float*)d_in[2];  // [L, N]
  const int*   esrc    = (const int*)d_in[3];    // [L, E]
  const int*   edst    = (const int*)d_in[4];    // [L, E]
  float*       out     = (float*)d_out;          // [B, N]

  // workspace (un-aliased; ~28.2 MB total)
  char* p = (char*)d_ws;
  float2* csr     = (float2*)p; p += (size_t)NL * NE * 8;            // 8 MB
  int*    row_ptr = (int*)p;    p += (size_t)NL * (NN + 1) * 4;
  int*    bcur    = (int*)p;    p += (size_t)NL * NBUK * 4;
  uint2*  stag    = (uint2*)p;  p += (size_t)NL * NBUK * BCAP * 8;   // 12 MB
  ushort* actA    = (ushort*)p; p += (size_t)NN * BATCH * 2;         // 4 MB
  ushort* actB    = (ushort*)p;                                      // 4 MB

  // ---- transpose x (block (0,0) zeroes all 512 bcur entries) ----
  transpose_in_k<<<dim3(NN / 32, BATCH / 32), dim3(32, 8), 0, stream>>>(x, actA, bcur);

  // ---- build CSR ----
  part_k<<<(NL * NE) / CHUNK, 256, 0, stream>>>(esrc, edst, weights, bcur, stag);
  place_k<<<NL * NBUK, 256, 0, stream>>>(stag, bcur, csr, row_ptr);

  for (int l = 0; l < NL; ++l) {
    gather_k<<<NN / 4, 256, 0, stream>>>((l & 1) ? actB : actA,
                                         (l & 1) ? actA : actB,
                                         csr + (size_t)l * NE,
                                         row_ptr + (size_t)l * (NN + 1),
                                         bias + (size_t)l * NN);
  }

  // actA [N,B] bf16 -> out [B,N] f32 (NL even -> result in actA)
  transpose_out_k<<<dim3(BATCH / 32, NN / 32), dim3(32, 8), 0, stream>>>(actA, out);
}